// Round 12
// baseline (163.795 us; speedup 1.0000x reference)
//
#include <hip/hip_runtime.h>
#include <hip/hip_bf16.h>
#include <math.h>

#define EPSF 1e-8f

// Icosphere div-1 connectivity, deterministically produced by _icosphere_div1().
static constexpr int FI[80][3] = {
  {0,12,14},{11,13,12},{5,14,13},{12,13,14},
  {0,14,16},{5,15,14},{1,16,15},{14,15,16},
  {0,16,18},{1,17,16},{7,18,17},{16,17,18},
  {0,18,20},{7,19,18},{10,20,19},{18,19,20},
  {0,20,12},{10,21,20},{11,12,21},{20,21,12},
  {1,15,23},{5,22,15},{9,23,22},{15,22,23},
  {5,13,25},{11,24,13},{4,25,24},{13,24,25},
  {11,21,27},{10,26,21},{2,27,26},{21,26,27},
  {10,19,29},{7,28,19},{6,29,28},{19,28,29},
  {7,17,31},{1,30,17},{8,31,30},{17,30,31},
  {3,32,34},{9,33,32},{4,34,33},{32,33,34},
  {3,34,36},{4,35,34},{2,36,35},{34,35,36},
  {3,36,38},{2,37,36},{6,38,37},{36,37,38},
  {3,38,40},{6,39,38},{8,40,39},{38,39,40},
  {3,40,32},{8,41,40},{9,32,41},{40,41,32},
  {4,33,25},{9,22,33},{5,25,22},{33,22,25},
  {2,35,27},{4,24,35},{11,27,24},{35,24,27},
  {6,37,29},{2,26,37},{10,29,26},{37,26,29},
  {8,39,31},{6,28,39},{7,31,28},{39,28,31},
  {9,41,23},{8,30,41},{1,23,30},{41,30,23}
};

// asin(s), s in [0,1]: A&S 4.4.46 8-coeff, |err| <= 2e-8 absolute (libm-grade).
__device__ __forceinline__ float asin_poly(float s) {
  float p = fmaf(s, -0.0012624911f, 0.0066700901f);
  p = fmaf(s, p, -0.0170881256f);
  p = fmaf(s, p,  0.0308918810f);
  p = fmaf(s, p, -0.0501743046f);
  p = fmaf(s, p,  0.0889789874f);
  p = fmaf(s, p, -0.2145988016f);
  p = fmaf(s, p,  1.5707963050f);
  return fmaf(-sqrtf(1.0f - s), p, 1.57079632679f);
}

// ---------------------------------------------------------------------------
// Phase 1: cage shrink (verified r7/r10) + init of mins/counters/loss for the
// chamfer phase (stream-ordered ahead of k_chamfer; 168*512 >= 49152).
// ---------------------------------------------------------------------------
__global__ __launch_bounds__(512) void k_cage(
    const float* __restrict__ catModel, const float* __restrict__ tv,
    const float* __restrict__ catKeys, const float* __restrict__ insKeys,
    const float* __restrict__ catInflu,
    float* __restrict__ cage, float* __restrict__ ncage,
    unsigned* __restrict__ mins, unsigned* __restrict__ cnt,
    float* __restrict__ loss)
{
  const int b = blockIdx.x / 42, v = blockIdx.x % 42;
  const int tid = threadIdx.x;
  const int lane = tid & 63, w = tid >> 6;

  {  // init for phase 3 (poisoned each launch by the harness)
    const int gi = blockIdx.x * 512 + tid;
    if (gi < 49152) mins[gi] = 0x7F800000u;   // +inf
    if (gi < 32)    cnt[gi]  = 0u;
    if (gi == 40)   loss[0]  = 0.0f;
  }

  const float c0x = tv[v], c0y = tv[42 + v], c0z = tv[84 + v];
  const float a = c0x*c0x + c0y*c0y + c0z*c0z;

  float pb2[12], pc[12];
  const float* P = catModel + (size_t)b * 6144 * 3;
  #pragma unroll
  for (int j = 0; j < 12; ++j) {
    int n = tid + j * 512;
    float px = P[n*3+0], py = P[n*3+1], pz = P[n*3+2];
    pb2[j] = -2.0f * (c0x*px + c0y*py + c0z*pz);
    pc[j]  = px*px + py*py + pz*pz;
  }

  __shared__ int mm[8];
  __shared__ float sfin;

  int tmin = 1000;
  float s = 1.0f;
  for (int t = 0; t < 100; ++t) {
    float ma = 1e30f, mb = 1e30f, mc = 1e30f, md = 1e30f;
    #pragma unroll
    for (int j = 0; j < 12; j += 4) {
      ma = fminf(ma, fmaf(fmaf(a, s, pb2[j+0]), s, pc[j+0]));
      mb = fminf(mb, fmaf(fmaf(a, s, pb2[j+1]), s, pc[j+1]));
      mc = fminf(mc, fmaf(fmaf(a, s, pb2[j+2]), s, pc[j+2]));
      md = fminf(md, fmaf(fmaf(a, s, pb2[j+3]), s, pc[j+3]));
    }
    float m = fminf(fminf(ma, mb), fminf(mc, md));
    if (m <= 0.16f && tmin == 1000) tmin = t;
    if (__all(tmin != 1000)) break;
    s *= 0.99f;
  }

  #pragma unroll
  for (int off = 32; off; off >>= 1)
    tmin = min(tmin, __shfl_xor(tmin, off, 64));
  if (lane == 0) mm[w] = tmin;
  __syncthreads();

  if (tid == 0) {
    int k = mm[0];
    #pragma unroll
    for (int i = 1; i < 8; ++i) k = min(k, mm[i]);
    if (k > 100) k = 100;
    float sf = 1.0f;                 // replicate reference's float rounding
    for (int i = 0; i < k; ++i) sf *= 0.99f;
    sfin = sf;
  }
  __syncthreads();

  if (tid < 3) {
    const int d = tid;
    const float cg_ = sfin * tv[d*42 + v];
    float off = 0.0f;
    #pragma unroll
    for (int k = 0; k < 8; ++k)
      off += (insKeys[(b*8+k)*3 + d] - catKeys[(b*8+k)*3 + d]) * catInflu[(b*8+k)*42 + v];
    cage [(b*42 + v)*3 + d] = cg_;
    ncage[(b*42 + v)*3 + d] = cg_ + off;
  }
}

// ---------------------------------------------------------------------------
// Phase 2: MVC + deform (verified r11: structure r7, rcp r10, asin_poly r11).
// ---------------------------------------------------------------------------
__global__ __launch_bounds__(256) void k_mvc(
    const float* __restrict__ catModel, const float* __restrict__ cage,
    const float* __restrict__ ncage,
    float* __restrict__ outCat, float* __restrict__ outDef)
{
  const int b    = blockIdx.x / 384;
  const int pblk = blockIdx.x % 384;
  const int lane = threadIdx.x & 63;
  const int w    = threadIdx.x >> 6;
  const int pt   = lane & 15;
  const int sub  = lane >> 4;
  const int slice = w*4 + sub;
  const int p    = pblk * 16 + pt;

  __shared__ float cv[126], nv[126];
  __shared__ unsigned sF[80];
  __shared__ float red[4][4][16];
  if (threadIdx.x < 126) {
    cv[threadIdx.x] = cage [b*126 + threadIdx.x];
    nv[threadIdx.x] = ncage[b*126 + threadIdx.x];
  }
  if (threadIdx.x < 80) {
    sF[threadIdx.x] = (unsigned)FI[threadIdx.x][0]
                    | ((unsigned)FI[threadIdx.x][1] << 8)
                    | ((unsigned)FI[threadIdx.x][2] << 16);
  }
  __syncthreads();

  const float qx = catModel[((size_t)b*6144 + p)*3 + 0];
  const float qy = catModel[((size_t)b*6144 + p)*3 + 1];
  const float qz = catModel[((size_t)b*6144 + p)*3 + 2];

  if (w == 1 && sub == 0) {   // passthrough copy (output 0)
    outCat[((size_t)b*6144 + p)*3 + 0] = qx;
    outCat[((size_t)b*6144 + p)*3 + 1] = qy;
    outCat[((size_t)b*6144 + p)*3 + 2] = qz;
  }

  float sW = 0.0f, dx = 0.0f, dy = 0.0f, dz = 0.0f;

  for (int ff = 0; ff < 5; ++ff) {
    const unsigned pk = sF[slice*5 + ff];
    const int i0 = pk & 255, i1 = (pk >> 8) & 255, i2 = pk >> 16;

    float e0x = cv[i0*3+0]-qx, e0y = cv[i0*3+1]-qy, e0z = cv[i0*3+2]-qz;
    float e1x = cv[i1*3+0]-qx, e1y = cv[i1*3+1]-qy, e1z = cv[i1*3+2]-qz;
    float e2x = cv[i2*3+0]-qx, e2y = cv[i2*3+1]-qy, e2z = cv[i2*3+2]-qz;
    float d0 = sqrtf(e0x*e0x + e0y*e0y + e0z*e0z);
    float d1 = sqrtf(e1x*e1x + e1y*e1y + e1z*e1z);
    float d2 = sqrtf(e2x*e2x + e2y*e2y + e2z*e2z);
    float r0 = __builtin_amdgcn_rcpf(fmaxf(d0, EPSF));
    float r1 = __builtin_amdgcn_rcpf(fmaxf(d1, EPSF));
    float r2 = __builtin_amdgcn_rcpf(fmaxf(d2, EPSF));
    float u0x = e0x*r0, u0y = e0y*r0, u0z = e0z*r0;
    float u1x = e1x*r1, u1y = e1y*r1, u1z = e1z*r1;
    float u2x = e2x*r2, u2y = e2y*r2, u2z = e2z*r2;

    float ax_ = u1x-u2x, ay_ = u1y-u2y, az_ = u1z-u2z;
    float bx_ = u2x-u0x, by_ = u2y-u0y, bz_ = u2z-u0z;
    float cx_ = u0x-u1x, cy_ = u0y-u1y, cz_ = u0z-u1z;
    float l0 = sqrtf(ax_*ax_ + ay_*ay_ + az_*az_);
    float l1 = sqrtf(bx_*bx_ + by_*by_ + bz_*bz_);
    float l2 = sqrtf(cx_*cx_ + cy_*cy_ + cz_*cz_);

    float s0 = fminf(0.5f*l0, 1.0f);
    float s1 = fminf(0.5f*l1, 1.0f);
    float s2 = fminf(0.5f*l2, 1.0f);
    float th0 = 2.0f*asin_poly(s0);
    float th1 = 2.0f*asin_poly(s1);
    float th2 = 2.0f*asin_poly(s2);
    float co0 = sqrtf(fmaxf(fmaf(-s0, s0, 1.0f), 0.0f));
    float co1 = sqrtf(fmaxf(fmaf(-s1, s1, 1.0f), 0.0f));
    float co2 = sqrtf(fmaxf(fmaf(-s2, s2, 1.0f), 0.0f));
    float st0 = 2.0f*s0*co0;   // sin(theta_k), exact identity
    float st1 = 2.0f*s1*co1;
    float st2 = 2.0f*s2*co2;

    // sin/cos of h = a0+a1+a2 (a_k = asin(s_k)) by angle-sum expansion
    float Sh = s0*co1*co2 + co0*s1*co2 + co0*co1*s2 - s0*s1*s2;
    float Ch = co0*co1*co2 - s0*s1*co2 - s0*co1*s2 - co0*s1*s2;
    // sin(h - theta_k) = Sh*cos(2ak) - Ch*sin(2ak)
    float sh0 = Sh*fmaf(-2.0f*s0, s0, 1.0f) - Ch*st0;
    float sh1 = Sh*fmaf(-2.0f*s1, s1, 1.0f) - Ch*st1;
    float sh2 = Sh*fmaf(-2.0f*s2, s2, 1.0f) - Ch*st2;

    float c0 = fmaf(2.0f*Sh*sh0, __builtin_amdgcn_rcpf(fmaxf(st1*st2, EPSF)), -1.0f);
    float c1 = fmaf(2.0f*Sh*sh1, __builtin_amdgcn_rcpf(fmaxf(st2*st0, EPSF)), -1.0f);
    float c2 = fmaf(2.0f*Sh*sh2, __builtin_amdgcn_rcpf(fmaxf(st0*st1, EPSF)), -1.0f);

    float det = u0x*(u1y*u2z - u1z*u2y)
              + u0y*(u1z*u2x - u1x*u2z)
              + u0z*(u1x*u2y - u1y*u2x);
    float sg = (det > 0.0f) ? 1.0f : ((det < 0.0f) ? -1.0f : 0.0f);
    float q0 = sg * sqrtf(fmaxf(fmaf(-c0, c0, 1.0f), 0.0f));
    float q1 = sg * sqrtf(fmaxf(fmaf(-c1, c1, 1.0f), 0.0f));
    float q2 = sg * sqrtf(fmaxf(fmaf(-c2, c2, 1.0f), 0.0f));
    bool valid = (fabsf(q0) > EPSF) && (fabsf(q1) > EPSF) && (fabsf(q2) > EPSF);

    float n0 = th0 - c1*th2 - c2*th1;
    float n1 = th1 - c2*th0 - c0*th2;
    float n2 = th2 - c0*th1 - c1*th0;
    float de0 = d0*st1*q2;
    float de1 = d1*st2*q0;
    float de2 = d2*st0*q1;
    de0 = (fabsf(de0) > EPSF) ? de0 : ((de0 >= 0.0f) ? EPSF : -EPSF);
    de1 = (fabsf(de1) > EPSF) ? de1 : ((de1 >= 0.0f) ? EPSF : -EPSF);
    de2 = (fabsf(de2) > EPSF) ? de2 : ((de2 >= 0.0f) ? EPSF : -EPSF);

    if (valid) {
      float w0 = n0 * __builtin_amdgcn_rcpf(de0);
      float w1 = n1 * __builtin_amdgcn_rcpf(de1);
      float w2 = n2 * __builtin_amdgcn_rcpf(de2);
      sW += w0 + w1 + w2;
      dx = fmaf(w0, nv[i0*3+0], fmaf(w1, nv[i1*3+0], fmaf(w2, nv[i2*3+0], dx)));
      dy = fmaf(w0, nv[i0*3+1], fmaf(w1, nv[i1*3+1], fmaf(w2, nv[i2*3+1], dy)));
      dz = fmaf(w0, nv[i0*3+2], fmaf(w1, nv[i1*3+2], fmaf(w2, nv[i2*3+2], dz)));
    }
  }

  // reduce over 4 sub-slices within the wave
  sW += __shfl_xor(sW, 16, 64); dx += __shfl_xor(dx, 16, 64);
  dy += __shfl_xor(dy, 16, 64); dz += __shfl_xor(dz, 16, 64);
  sW += __shfl_xor(sW, 32, 64); dx += __shfl_xor(dx, 32, 64);
  dy += __shfl_xor(dy, 32, 64); dz += __shfl_xor(dz, 32, 64);

  if (sub == 0) {
    red[w][0][pt] = sW; red[w][1][pt] = dx;
    red[w][2][pt] = dy; red[w][3][pt] = dz;
  }
  __syncthreads();

  if (w == 0 && sub == 0) {
    float S = red[0][0][pt] + red[1][0][pt] + red[2][0][pt] + red[3][0][pt];
    float X = red[0][1][pt] + red[1][1][pt] + red[2][1][pt] + red[3][1][pt];
    float Y = red[0][2][pt] + red[1][2][pt] + red[2][2][pt] + red[3][2][pt];
    float Z = red[0][3][pt] + red[1][3][pt] + red[2][3][pt] + red[3][3][pt];
    S = (fabsf(S) > EPSF) ? S : EPSF;
    float inv = 1.0f / S;
    outDef[((size_t)b*6144 + p)*3 + 0] = X * inv;
    outDef[((size_t)b*6144 + p)*3 + 1] = Y * inv;
    outDef[((size_t)b*6144 + p)*3 + 2] = Z * inv;
  }
}

// ---------------------------------------------------------------------------
// Phase 3: chamfer + fused loss. 768 blocks; global atomicMin mins (r5/r6
// verified). Each group (dir,b,rt) = 24 col-chunk blocks shares a done
// counter; the 24th block re-reads its own 1536 rows' now-final mins via
// atomicOr(p,0) (L2-coherent) and atomicAdds a pre-scaled partial into loss.
// 32 group-last blocks reduce in parallel -> no single-block bottleneck.
// ---------------------------------------------------------------------------
__global__ __launch_bounds__(256) void k_chamfer(
    const float* __restrict__ def, const float* __restrict__ ins,
    float* __restrict__ outIns, unsigned* __restrict__ mins,
    unsigned* __restrict__ cnt, float* __restrict__ loss)
{
  const int bx  = blockIdx.x;
  const int dir = (bx >= 384) ? 1 : 0;
  const int r   = bx - dir*384;
  const int b   = r / 96;
  const int rt  = (r % 96) / 24;
  const int cc  = r % 24;
  const int tid = threadIdx.x;
  const int grp = (dir*4 + b)*4 + rt;    // 0..31

  const float* R = (dir ? ins : def) + (size_t)b * 6144 * 3;
  const float* C = (dir ? def : ins) + (size_t)b * 6144 * 3;

  const int r0 = rt*1536 + tid;
  float rx[6], ry[6], rz[6];
  #pragma unroll
  for (int k = 0; k < 6; ++k) {
    int rr = r0 + k*256;
    rx[k] = R[rr*3+0]; ry[k] = R[rr*3+1]; rz[k] = R[rr*3+2];
  }

  if (dir == 1 && cc == 0) {   // passthrough copy (output 1)
    #pragma unroll
    for (int k = 0; k < 6; ++k) {
      int rr = r0 + k*256;
      outIns[(size_t)(b*6144 + rr)*3+0] = rx[k];
      outIns[(size_t)(b*6144 + rr)*3+1] = ry[k];
      outIns[(size_t)(b*6144 + rr)*3+2] = rz[k];
    }
  }

  __shared__ float4 tile[256];
  {
    int c = cc*256 + tid;
    float cx = C[c*3+0], cy = C[c*3+1], cz = C[c*3+2];
    tile[tid] = make_float4(-2.0f*cx, -2.0f*cy, -2.0f*cz, cx*cx + cy*cy + cz*cz);
  }
  __syncthreads();

  float m[6];
  #pragma unroll
  for (int k = 0; k < 6; ++k) m[k] = 1e30f;

  #pragma unroll 8
  for (int j = 0; j < 256; ++j) {
    float4 q = tile[j];
    #pragma unroll
    for (int k = 0; k < 6; ++k)
      m[k] = fminf(m[k], fmaf(q.x, rx[k], fmaf(q.y, ry[k], fmaf(q.z, rz[k], q.w))));
  }

  unsigned* mo = mins + dir*24576 + b*6144;
  #pragma unroll
  for (int k = 0; k < 6; ++k)
    atomicMin(&mo[r0 + k*256],
              __float_as_uint(m[k] + (rx[k]*rx[k] + ry[k]*ry[k] + rz[k]*rz[k])));

  // ---- group completion: last of the 24 chunk-blocks reduces its rows ----
  __threadfence();          // make this block's atomics device-visible
  __syncthreads();          // all threads' atomics issued+fenced
  __shared__ int lastFlag;
  if (tid == 0) lastFlag = (atomicAdd(&cnt[grp], 1u) == 23u) ? 1 : 0;
  __syncthreads();

  if (lastFlag) {
    float s = 0.0f;
    #pragma unroll
    for (int k = 0; k < 6; ++k)
      s += __uint_as_float(atomicOr(&mo[r0 + k*256], 0u));  // coherent read
    #pragma unroll
    for (int off = 32; off; off >>= 1) s += __shfl_xor(s, off, 64);
    __shared__ float red2[4];
    if ((tid & 63) == 0) red2[tid >> 6] = s;
    __syncthreads();
    if (tid == 0)
      atomicAdd(loss, (red2[0] + red2[1] + red2[2] + red2[3]) * (1.0f / 24576.0f));
  }
}

// ---------------------------------------------------------------------------
extern "C" void kernel_launch(void* const* d_in, const int* in_sizes, int n_in,
                              void* d_out, int out_size, void* d_ws, size_t ws_size,
                              hipStream_t stream) {
  const float* catModel = (const float*)d_in[0];  // (4,6144,3)
  const float* catKeys  = (const float*)d_in[1];  // (4,8,3)
  const float* catInflu = (const float*)d_in[2];  // (4,8,42)
  const float* insKeys  = (const float*)d_in[3];  // (4,8,3)
  const float* insModel = (const float*)d_in[4];  // (4,6144,3)
  const float* tv       = (const float*)d_in[5];  // (1,3,42)
  // d_in[6] = template_faces, baked in as FI[][]

  float* out = (float*)d_out;       // [catModel | insModel | deformed | loss]
  float* ws  = (float*)d_ws;
  float*    cage  = ws;                        // 504 floats (pad to 512)
  float*    ncage = ws + 512;                  // 504 floats
  unsigned* mins  = (unsigned*)(ws + 1024);    // 49152 uints
  unsigned* cnt   = (unsigned*)(ws + 1024 + 49152);  // 32 uints

  float* outCat = out;
  float* outIns = out + 73728;
  float* outDef = out + 147456;
  float* loss   = out + 221184;

  k_cage<<<168, 512, 0, stream>>>(catModel, tv, catKeys, insKeys, catInflu,
                                  cage, ncage, mins, cnt, loss);
  k_mvc <<<1536, 256, 0, stream>>>(catModel, cage, ncage, outCat, outDef);
  k_chamfer<<<768, 256, 0, stream>>>(outDef, insModel, outIns, mins, cnt, loss);
}

// Round 13
// 132.370 us; speedup vs baseline: 1.2374x; 1.2374x over previous
//
#include <hip/hip_runtime.h>
#include <hip/hip_bf16.h>
#include <math.h>

#define EPSF 1e-8f

// Icosphere div-1 connectivity, deterministically produced by _icosphere_div1().
static constexpr int FI[80][3] = {
  {0,12,14},{11,13,12},{5,14,13},{12,13,14},
  {0,14,16},{5,15,14},{1,16,15},{14,15,16},
  {0,16,18},{1,17,16},{7,18,17},{16,17,18},
  {0,18,20},{7,19,18},{10,20,19},{18,19,20},
  {0,20,12},{10,21,20},{11,12,21},{20,21,12},
  {1,15,23},{5,22,15},{9,23,22},{15,22,23},
  {5,13,25},{11,24,13},{4,25,24},{13,24,25},
  {11,21,27},{10,26,21},{2,27,26},{21,26,27},
  {10,19,29},{7,28,19},{6,29,28},{19,28,29},
  {7,17,31},{1,30,17},{8,31,30},{17,30,31},
  {3,32,34},{9,33,32},{4,34,33},{32,33,34},
  {3,34,36},{4,35,34},{2,36,35},{34,35,36},
  {3,36,38},{2,37,36},{6,38,37},{36,37,38},
  {3,38,40},{6,39,38},{8,40,39},{38,39,40},
  {3,40,32},{8,41,40},{9,32,41},{40,41,32},
  {4,33,25},{9,22,33},{5,25,22},{33,22,25},
  {2,35,27},{4,24,35},{11,27,24},{35,24,27},
  {6,37,29},{2,26,37},{10,29,26},{37,26,29},
  {8,39,31},{6,28,39},{7,31,28},{39,28,31},
  {9,41,23},{8,30,41},{1,23,30},{41,30,23}
};

// asin(s), s in [0,1]: A&S 4.4.46 8-coeff, |err| <= 2e-8 absolute (libm-grade).
__device__ __forceinline__ float asin_poly(float s) {
  float p = fmaf(s, -0.0012624911f, 0.0066700901f);
  p = fmaf(s, p, -0.0170881256f);
  p = fmaf(s, p,  0.0308918810f);
  p = fmaf(s, p, -0.0501743046f);
  p = fmaf(s, p,  0.0889789874f);
  p = fmaf(s, p, -0.2145988016f);
  p = fmaf(s, p,  1.5707963050f);
  return fmaf(-sqrtf(1.0f - s), p, 1.57079632679f);
}

// ---------------------------------------------------------------------------
// Phase 1: cage shrink (verified r7/r10/r11). Per-thread first-trigger tmin,
// single post-loop reduce, per-wave early exit. 512 thr/block.
// ---------------------------------------------------------------------------
__global__ __launch_bounds__(512) void k_cage(
    const float* __restrict__ catModel, const float* __restrict__ tv,
    const float* __restrict__ catKeys, const float* __restrict__ insKeys,
    const float* __restrict__ catInflu,
    float* __restrict__ cage, float* __restrict__ ncage)
{
  const int b = blockIdx.x / 42, v = blockIdx.x % 42;
  const int tid = threadIdx.x;
  const int lane = tid & 63, w = tid >> 6;
  const float c0x = tv[v], c0y = tv[42 + v], c0z = tv[84 + v];
  const float a = c0x*c0x + c0y*c0y + c0z*c0z;

  float pb2[12], pc[12];
  const float* P = catModel + (size_t)b * 6144 * 3;
  #pragma unroll
  for (int j = 0; j < 12; ++j) {
    int n = tid + j * 512;
    float px = P[n*3+0], py = P[n*3+1], pz = P[n*3+2];
    pb2[j] = -2.0f * (c0x*px + c0y*py + c0z*pz);
    pc[j]  = px*px + py*py + pz*pz;
  }

  __shared__ int mm[8];
  __shared__ float sfin;

  int tmin = 1000;
  float s = 1.0f;
  for (int t = 0; t < 100; ++t) {
    float ma = 1e30f, mb = 1e30f, mc = 1e30f, md = 1e30f;
    #pragma unroll
    for (int j = 0; j < 12; j += 4) {
      ma = fminf(ma, fmaf(fmaf(a, s, pb2[j+0]), s, pc[j+0]));
      mb = fminf(mb, fmaf(fmaf(a, s, pb2[j+1]), s, pc[j+1]));
      mc = fminf(mc, fmaf(fmaf(a, s, pb2[j+2]), s, pc[j+2]));
      md = fminf(md, fmaf(fmaf(a, s, pb2[j+3]), s, pc[j+3]));
    }
    float m = fminf(fminf(ma, mb), fminf(mc, md));
    if (m <= 0.16f && tmin == 1000) tmin = t;
    if (__all(tmin != 1000)) break;
    s *= 0.99f;
  }

  #pragma unroll
  for (int off = 32; off; off >>= 1)
    tmin = min(tmin, __shfl_xor(tmin, off, 64));
  if (lane == 0) mm[w] = tmin;
  __syncthreads();

  if (tid == 0) {
    int k = mm[0];
    #pragma unroll
    for (int i = 1; i < 8; ++i) k = min(k, mm[i]);
    if (k > 100) k = 100;
    float sf = 1.0f;                 // replicate reference's float rounding
    for (int i = 0; i < k; ++i) sf *= 0.99f;
    sfin = sf;
  }
  __syncthreads();

  if (tid < 3) {
    const int d = tid;
    const float cg_ = sfin * tv[d*42 + v];
    float off = 0.0f;
    #pragma unroll
    for (int k = 0; k < 8; ++k)
      off += (insKeys[(b*8+k)*3 + d] - catKeys[(b*8+k)*3 + d]) * catInflu[(b*8+k)*42 + v];
    cage [(b*42 + v)*3 + d] = cg_;
    ncage[(b*42 + v)*3 + d] = cg_ + off;
  }
}

// ---------------------------------------------------------------------------
// Phase 2: MVC + deform (verified r11: structure r7, rcp r10, asin_poly r11).
// ---------------------------------------------------------------------------
__global__ __launch_bounds__(256) void k_mvc(
    const float* __restrict__ catModel, const float* __restrict__ cage,
    const float* __restrict__ ncage,
    float* __restrict__ outCat, float* __restrict__ outDef)
{
  const int b    = blockIdx.x / 384;
  const int pblk = blockIdx.x % 384;
  const int lane = threadIdx.x & 63;
  const int w    = threadIdx.x >> 6;
  const int pt   = lane & 15;
  const int sub  = lane >> 4;
  const int slice = w*4 + sub;
  const int p    = pblk * 16 + pt;

  __shared__ float cv[126], nv[126];
  __shared__ unsigned sF[80];
  __shared__ float red[4][4][16];
  if (threadIdx.x < 126) {
    cv[threadIdx.x] = cage [b*126 + threadIdx.x];
    nv[threadIdx.x] = ncage[b*126 + threadIdx.x];
  }
  if (threadIdx.x < 80) {
    sF[threadIdx.x] = (unsigned)FI[threadIdx.x][0]
                    | ((unsigned)FI[threadIdx.x][1] << 8)
                    | ((unsigned)FI[threadIdx.x][2] << 16);
  }
  __syncthreads();

  const float qx = catModel[((size_t)b*6144 + p)*3 + 0];
  const float qy = catModel[((size_t)b*6144 + p)*3 + 1];
  const float qz = catModel[((size_t)b*6144 + p)*3 + 2];

  if (w == 1 && sub == 0) {   // passthrough copy (output 0)
    outCat[((size_t)b*6144 + p)*3 + 0] = qx;
    outCat[((size_t)b*6144 + p)*3 + 1] = qy;
    outCat[((size_t)b*6144 + p)*3 + 2] = qz;
  }

  float sW = 0.0f, dx = 0.0f, dy = 0.0f, dz = 0.0f;

  for (int ff = 0; ff < 5; ++ff) {
    const unsigned pk = sF[slice*5 + ff];
    const int i0 = pk & 255, i1 = (pk >> 8) & 255, i2 = pk >> 16;

    float e0x = cv[i0*3+0]-qx, e0y = cv[i0*3+1]-qy, e0z = cv[i0*3+2]-qz;
    float e1x = cv[i1*3+0]-qx, e1y = cv[i1*3+1]-qy, e1z = cv[i1*3+2]-qz;
    float e2x = cv[i2*3+0]-qx, e2y = cv[i2*3+1]-qy, e2z = cv[i2*3+2]-qz;
    float d0 = sqrtf(e0x*e0x + e0y*e0y + e0z*e0z);
    float d1 = sqrtf(e1x*e1x + e1y*e1y + e1z*e1z);
    float d2 = sqrtf(e2x*e2x + e2y*e2y + e2z*e2z);
    float r0 = __builtin_amdgcn_rcpf(fmaxf(d0, EPSF));
    float r1 = __builtin_amdgcn_rcpf(fmaxf(d1, EPSF));
    float r2 = __builtin_amdgcn_rcpf(fmaxf(d2, EPSF));
    float u0x = e0x*r0, u0y = e0y*r0, u0z = e0z*r0;
    float u1x = e1x*r1, u1y = e1y*r1, u1z = e1z*r1;
    float u2x = e2x*r2, u2y = e2y*r2, u2z = e2z*r2;

    float ax_ = u1x-u2x, ay_ = u1y-u2y, az_ = u1z-u2z;
    float bx_ = u2x-u0x, by_ = u2y-u0y, bz_ = u2z-u0z;
    float cx_ = u0x-u1x, cy_ = u0y-u1y, cz_ = u0z-u1z;
    float l0 = sqrtf(ax_*ax_ + ay_*ay_ + az_*az_);
    float l1 = sqrtf(bx_*bx_ + by_*by_ + bz_*bz_);
    float l2 = sqrtf(cx_*cx_ + cy_*cy_ + cz_*cz_);

    float s0 = fminf(0.5f*l0, 1.0f);
    float s1 = fminf(0.5f*l1, 1.0f);
    float s2 = fminf(0.5f*l2, 1.0f);
    float th0 = 2.0f*asin_poly(s0);
    float th1 = 2.0f*asin_poly(s1);
    float th2 = 2.0f*asin_poly(s2);
    float co0 = sqrtf(fmaxf(fmaf(-s0, s0, 1.0f), 0.0f));
    float co1 = sqrtf(fmaxf(fmaf(-s1, s1, 1.0f), 0.0f));
    float co2 = sqrtf(fmaxf(fmaf(-s2, s2, 1.0f), 0.0f));
    float st0 = 2.0f*s0*co0;   // sin(theta_k), exact identity
    float st1 = 2.0f*s1*co1;
    float st2 = 2.0f*s2*co2;

    // sin/cos of h = a0+a1+a2 (a_k = asin(s_k)) by angle-sum expansion
    float Sh = s0*co1*co2 + co0*s1*co2 + co0*co1*s2 - s0*s1*s2;
    float Ch = co0*co1*co2 - s0*s1*co2 - s0*co1*s2 - co0*s1*s2;
    // sin(h - theta_k) = Sh*cos(2ak) - Ch*sin(2ak)
    float sh0 = Sh*fmaf(-2.0f*s0, s0, 1.0f) - Ch*st0;
    float sh1 = Sh*fmaf(-2.0f*s1, s1, 1.0f) - Ch*st1;
    float sh2 = Sh*fmaf(-2.0f*s2, s2, 1.0f) - Ch*st2;

    float c0 = fmaf(2.0f*Sh*sh0, __builtin_amdgcn_rcpf(fmaxf(st1*st2, EPSF)), -1.0f);
    float c1 = fmaf(2.0f*Sh*sh1, __builtin_amdgcn_rcpf(fmaxf(st2*st0, EPSF)), -1.0f);
    float c2 = fmaf(2.0f*Sh*sh2, __builtin_amdgcn_rcpf(fmaxf(st0*st1, EPSF)), -1.0f);

    float det = u0x*(u1y*u2z - u1z*u2y)
              + u0y*(u1z*u2x - u1x*u2z)
              + u0z*(u1x*u2y - u1y*u2x);
    float sg = (det > 0.0f) ? 1.0f : ((det < 0.0f) ? -1.0f : 0.0f);
    float q0 = sg * sqrtf(fmaxf(fmaf(-c0, c0, 1.0f), 0.0f));
    float q1 = sg * sqrtf(fmaxf(fmaf(-c1, c1, 1.0f), 0.0f));
    float q2 = sg * sqrtf(fmaxf(fmaf(-c2, c2, 1.0f), 0.0f));
    bool valid = (fabsf(q0) > EPSF) && (fabsf(q1) > EPSF) && (fabsf(q2) > EPSF);

    float n0 = th0 - c1*th2 - c2*th1;
    float n1 = th1 - c2*th0 - c0*th2;
    float n2 = th2 - c0*th1 - c1*th0;
    float de0 = d0*st1*q2;
    float de1 = d1*st2*q0;
    float de2 = d2*st0*q1;
    de0 = (fabsf(de0) > EPSF) ? de0 : ((de0 >= 0.0f) ? EPSF : -EPSF);
    de1 = (fabsf(de1) > EPSF) ? de1 : ((de1 >= 0.0f) ? EPSF : -EPSF);
    de2 = (fabsf(de2) > EPSF) ? de2 : ((de2 >= 0.0f) ? EPSF : -EPSF);

    if (valid) {
      float w0 = n0 * __builtin_amdgcn_rcpf(de0);
      float w1 = n1 * __builtin_amdgcn_rcpf(de1);
      float w2 = n2 * __builtin_amdgcn_rcpf(de2);
      sW += w0 + w1 + w2;
      dx = fmaf(w0, nv[i0*3+0], fmaf(w1, nv[i1*3+0], fmaf(w2, nv[i2*3+0], dx)));
      dy = fmaf(w0, nv[i0*3+1], fmaf(w1, nv[i1*3+1], fmaf(w2, nv[i2*3+1], dy)));
      dz = fmaf(w0, nv[i0*3+2], fmaf(w1, nv[i1*3+2], fmaf(w2, nv[i2*3+2], dz)));
    }
  }

  // reduce over 4 sub-slices within the wave
  sW += __shfl_xor(sW, 16, 64); dx += __shfl_xor(dx, 16, 64);
  dy += __shfl_xor(dy, 16, 64); dz += __shfl_xor(dz, 16, 64);
  sW += __shfl_xor(sW, 32, 64); dx += __shfl_xor(dx, 32, 64);
  dy += __shfl_xor(dy, 32, 64); dz += __shfl_xor(dz, 32, 64);

  if (sub == 0) {
    red[w][0][pt] = sW; red[w][1][pt] = dx;
    red[w][2][pt] = dy; red[w][3][pt] = dz;
  }
  __syncthreads();

  if (w == 0 && sub == 0) {
    float S = red[0][0][pt] + red[1][0][pt] + red[2][0][pt] + red[3][0][pt];
    float X = red[0][1][pt] + red[1][1][pt] + red[2][1][pt] + red[3][1][pt];
    float Y = red[0][2][pt] + red[1][2][pt] + red[2][2][pt] + red[3][2][pt];
    float Z = red[0][3][pt] + red[1][3][pt] + red[2][3][pt] + red[3][3][pt];
    S = (fabsf(S) > EPSF) ? S : EPSF;
    float inv = 1.0f / S;
    outDef[((size_t)b*6144 + p)*3 + 0] = X * inv;
    outDef[((size_t)b*6144 + p)*3 + 1] = Y * inv;
    outDef[((size_t)b*6144 + p)*3 + 2] = Z * inv;
  }
}

// ---------------------------------------------------------------------------
// Phase 3: chamfer, atomic-free partials (r7 math), RE-SHAPED: 512 thr/block
// x 3 rows/thread (was 256 x 6). Same 768 blocks, same 1536-row tiles
// (rows rt*1536 + tid + k*512 cover the identical set), same col order ->
// partial[] is bit-identical. Occupancy cap 12 -> 24 waves/CU.
// ---------------------------------------------------------------------------
__global__ __launch_bounds__(512) void k_chamfer(
    const float* __restrict__ def, const float* __restrict__ ins,
    float* __restrict__ outIns, float* __restrict__ partial,
    float* __restrict__ loss)
{
  const int bx  = blockIdx.x;
  const int dir = (bx >= 384) ? 1 : 0;
  const int r   = bx - dir*384;
  const int b   = r / 96;
  const int rt  = (r % 96) / 24;
  const int cc  = r % 24;
  const int tid = threadIdx.x;

  if (bx == 0 && tid == 0) loss[0] = 0.0f;

  const float* R = (dir ? ins : def) + (size_t)b * 6144 * 3;
  const float* C = (dir ? def : ins) + (size_t)b * 6144 * 3;

  const int r0 = rt*1536 + tid;
  float rx[3], ry[3], rz[3];
  #pragma unroll
  for (int k = 0; k < 3; ++k) {
    int rr = r0 + k*512;
    rx[k] = R[rr*3+0]; ry[k] = R[rr*3+1]; rz[k] = R[rr*3+2];
  }

  if (dir == 1 && cc == 0) {   // passthrough copy (output 1)
    #pragma unroll
    for (int k = 0; k < 3; ++k) {
      int rr = r0 + k*512;
      outIns[(size_t)(b*6144 + rr)*3+0] = rx[k];
      outIns[(size_t)(b*6144 + rr)*3+1] = ry[k];
      outIns[(size_t)(b*6144 + rr)*3+2] = rz[k];
    }
  }

  __shared__ float4 tile[256];
  if (tid < 256) {
    int c = cc*256 + tid;
    float cx = C[c*3+0], cy = C[c*3+1], cz = C[c*3+2];
    tile[tid] = make_float4(-2.0f*cx, -2.0f*cy, -2.0f*cz, cx*cx + cy*cy + cz*cz);
  }
  __syncthreads();

  float m[3];
  #pragma unroll
  for (int k = 0; k < 3; ++k) m[k] = 1e30f;

  #pragma unroll 8
  for (int j = 0; j < 256; ++j) {
    float4 q = tile[j];
    #pragma unroll
    for (int k = 0; k < 3; ++k)
      m[k] = fminf(m[k], fmaf(q.x, rx[k], fmaf(q.y, ry[k], fmaf(q.z, rz[k], q.w))));
  }

  float* po = partial + ((size_t)((dir*4 + b)*24 + cc)) * 6144;
  #pragma unroll
  for (int k = 0; k < 3; ++k) {
    int rr = r0 + k*512;
    po[rr] = m[k] + (rx[k]*rx[k] + ry[k]*ry[k] + rz[k]*rz[k]);
  }
}

// ---------------------------------------------------------------------------
// Phase 4: loss (verified r7). Min over 24 chunks/row, then sum-reduce.
// ---------------------------------------------------------------------------
__global__ __launch_bounds__(256) void k_loss(
    const float* __restrict__ partial, float* __restrict__ loss)
{
  const int base = blockIdx.x * 512 + threadIdx.x * 2;
  float s = 0.0f;
  #pragma unroll
  for (int g = base; g < base + 2; ++g) {
    const int db = g / 6144, row = g % 6144;
    const float* pp = partial + (size_t)db * 24 * 6144 + row;
    float v = 1e30f;
    #pragma unroll
    for (int c = 0; c < 24; ++c) v = fminf(v, pp[c * 6144]);
    s += v;
  }
  #pragma unroll
  for (int off = 32; off; off >>= 1) s += __shfl_xor(s, off, 64);
  __shared__ float red[4];
  if ((threadIdx.x & 63) == 0) red[threadIdx.x >> 6] = s;
  __syncthreads();
  if (threadIdx.x == 0)
    atomicAdd(loss, (red[0] + red[1] + red[2] + red[3]) * (1.0f / 24576.0f));
}

// ---------------------------------------------------------------------------
extern "C" void kernel_launch(void* const* d_in, const int* in_sizes, int n_in,
                              void* d_out, int out_size, void* d_ws, size_t ws_size,
                              hipStream_t stream) {
  const float* catModel = (const float*)d_in[0];  // (4,6144,3)
  const float* catKeys  = (const float*)d_in[1];  // (4,8,3)
  const float* catInflu = (const float*)d_in[2];  // (4,8,42)
  const float* insKeys  = (const float*)d_in[3];  // (4,8,3)
  const float* insModel = (const float*)d_in[4];  // (4,6144,3)
  const float* tv       = (const float*)d_in[5];  // (1,3,42)
  // d_in[6] = template_faces, baked in as FI[][]

  float* out = (float*)d_out;       // [catModel | insModel | deformed | loss]
  float* ws  = (float*)d_ws;
  float* cage    = ws;                  // 504 floats (pad to 512)
  float* ncage   = ws + 512;            // 504 floats
  float* partial = ws + 1024;           // 2*4*24*6144 floats

  float* outCat = out;
  float* outIns = out + 73728;
  float* outDef = out + 147456;
  float* loss   = out + 221184;

  k_cage<<<168, 512, 0, stream>>>(catModel, tv, catKeys, insKeys, catInflu, cage, ncage);
  k_mvc <<<1536, 256, 0, stream>>>(catModel, cage, ncage, outCat, outDef);
  k_chamfer<<<768, 512, 0, stream>>>(outDef, insModel, outIns, partial, loss);
  k_loss<<<96, 256, 0, stream>>>(partial, loss);
}